// Round 11
// baseline (9745.500 us; speedup 1.0000x reference)
//
#include <hip/hip_runtime.h>
#include <cstdint>
#include <cstddef>

#define N_IN   128
#define N_REC  512
#define N_OUT  20
#define N_T    1000
#define N_B    64
#define NSTEP  999
// f32(exp(-0.05)) — what numpy/jax actually multiply f32 arrays by
#define ALPHA_F 0.95122945308685302734375f
#define KAPPA_F 0.95122945308685302734375f

typedef unsigned long long ull;

// ---- ws layout (bytes) ----
#define OFF_WINT   0ull            // 128*512*4  = 262,144   w_inT[k][i]
#define OFF_WRECT  262144ull       // 513*512*4  = 1,050,624 w_recT[j][i], diag=0, row512=0
#define OFF_ZMASK  1312768ull      // 64*999*8*8 = 4,091,904
#define OFF_U      5404672ull      // 64*999*20*4= 5,114,880
#define OFF_GMASK  10519552ull     // 64*2*4*2*8 = 8,192
#define OFF_GTAG   10527744ull     // 64*4*2*4   = 2,048 (+pad)
#define OFF_XPROJ  10531840ull     // 64*999*512*4 = 130,940,928
#define NEED_PRE   (OFF_XPROJ + 130940928ull)

#define SENT_OFF   (512 << 11)     // byte offset of the zero pad row

// light barrier: LDS-ordering only, no vmcnt(0) drain
__device__ __forceinline__ void bar_lgkm() {
  asm volatile("s_waitcnt lgkmcnt(0)" ::: "memory");
  __builtin_amdgcn_s_barrier();
}

// ------- setup: transposes (+zero diag, +zero pad row 512) + zero gtag ------
__global__ __launch_bounds__(256) void k_setup(
    const float* __restrict__ w_in, const float* __restrict__ w_rec,
    float* __restrict__ w_inT, float* __restrict__ w_recT,
    unsigned int* __restrict__ gtag) {
  int idx = blockIdx.x * 256 + threadIdx.x;
  if (idx < N_IN * N_REC) {                     // w_inT[k][i] = w_in[i][k]
    int k = idx >> 9, i = idx & 511;
    w_inT[idx] = w_in[i * N_IN + k];
  } else if (idx < N_IN * N_REC + 513 * N_REC) {
    int r = idx - N_IN * N_REC;                 // w_recT[j][i] = w_rec[i][j]*(i!=j)
    int j = r >> 9, i = r & 511;
    w_recT[r] = (j < N_REC && i != j) ? w_rec[i * N_REC + j] : 0.0f;
  } else if (idx < N_IN * N_REC + 513 * N_REC + 512) {
    gtag[idx - (N_IN * N_REC + 513 * N_REC)] = 0u;   // sync tags start at 0
  }
}

// ---- A: xproj[s][i] = sequential ascending-k f32 FMA chain (BLAS order) ----
#define XROWS 48
__global__ __launch_bounds__(256) void k_xprojE(
    const float* __restrict__ x, const float* __restrict__ w_inT,
    float* __restrict__ xproj) {
  __shared__ float xs[XROWS][N_IN];       // 24 KiB
  int tid = threadIdx.x;
  int R0 = blockIdx.x * XROWS;
  #pragma unroll
  for (int u = 0; u < 6; ++u) {
    int id = tid + u * 256;               // 1536 float4 slots = 48 rows
    int rr = id >> 5, c = id & 31;
    int s = R0 + rr;
    int b = s / NSTEP, t = s - b * NSTEP;
    float4 xv = ((const float4*)x)[(size_t)(b * N_T + t) * 32 + c];
    xs[rr][4 * c]     = xv.x;
    xs[rr][4 * c + 1] = xv.y;
    xs[rr][4 * c + 2] = xv.z;
    xs[rr][4 * c + 3] = xv.w;
  }
  __syncthreads();
  float acc[XROWS][2];
  #pragma unroll
  for (int r = 0; r < XROWS; ++r) { acc[r][0] = 0.f; acc[r][1] = 0.f; }
  for (int k = 0; k < N_IN; ++k) {
    float wa = w_inT[k * N_REC + tid];
    float wb = w_inT[k * N_REC + tid + 256];
    #pragma unroll
    for (int r = 0; r < XROWS; ++r) {
      acc[r][0] = fmaf(xs[r][k], wa, acc[r][0]);
      acc[r][1] = fmaf(xs[r][k], wb, acc[r][1]);
    }
  }
  #pragma unroll
  for (int r = 0; r < XROWS; ++r) {
    size_t o0 = (size_t)(R0 + r) * N_REC + tid;
    xproj[o0]       = acc[r][0];
    xproj[o0 + 256] = acc[r][1];
  }
}

// ---- gather primitives: 16 indices (byte offsets) / 16 saddr loads ---------
struct F16R { float f[16]; };
struct I16  { int4 a, b, c, d; };

__device__ __forceinline__ void iload16(I16& r, const int* __restrict__ L, int base) {
  r.a = *(const int4*)(L + base);
  r.b = *(const int4*)(L + base + 4);
  r.c = *(const int4*)(L + base + 8);
  r.d = *(const int4*)(L + base + 12);
}

__device__ __forceinline__ void gload16i(F16R& r, const I16& I,
                                         const char* __restrict__ wb, int t4) {
  r.f[0]  = *(const float*)(wb + (uint32_t)(I.a.x + t4));
  r.f[1]  = *(const float*)(wb + (uint32_t)(I.a.y + t4));
  r.f[2]  = *(const float*)(wb + (uint32_t)(I.a.z + t4));
  r.f[3]  = *(const float*)(wb + (uint32_t)(I.a.w + t4));
  r.f[4]  = *(const float*)(wb + (uint32_t)(I.b.x + t4));
  r.f[5]  = *(const float*)(wb + (uint32_t)(I.b.y + t4));
  r.f[6]  = *(const float*)(wb + (uint32_t)(I.b.z + t4));
  r.f[7]  = *(const float*)(wb + (uint32_t)(I.b.w + t4));
  r.f[8]  = *(const float*)(wb + (uint32_t)(I.c.x + t4));
  r.f[9]  = *(const float*)(wb + (uint32_t)(I.c.y + t4));
  r.f[10] = *(const float*)(wb + (uint32_t)(I.c.z + t4));
  r.f[11] = *(const float*)(wb + (uint32_t)(I.c.w + t4));
  r.f[12] = *(const float*)(wb + (uint32_t)(I.d.x + t4));
  r.f[13] = *(const float*)(wb + (uint32_t)(I.d.y + t4));
  r.f[14] = *(const float*)(wb + (uint32_t)(I.d.z + t4));
  r.f[15] = *(const float*)(wb + (uint32_t)(I.d.w + t4));
}

__device__ __forceinline__ float add16(float rec, const F16R& r) {
  #pragma unroll
  for (int u = 0; u < 16; ++u) rec = __fadd_rn(rec, r.f[u]);
  return rec;
}

// ---- B: split scan — 4 parts x 128 threads per batch; mask sync via L2/L3 --
template <bool PRE>
__global__ __launch_bounds__(128, 1) void k_scanS(
    const float* __restrict__ xproj, const float* __restrict__ x,
    const float* __restrict__ w_inT, const float* __restrict__ w_recT,
    ull* __restrict__ zmask, ull* __restrict__ gmask,
    unsigned int* __restrict__ gtag) {
  __shared__ __align__(16) int list[512];   // compacted ascending j (byte offs)
  __shared__ ull zbuf[8];                   // full 512-bit mask of step t-1
  __shared__ float xrow[2][N_IN];           // PRE=false only
  int tid = threadIdx.x;
  int bb = blockIdx.x;
  int b = bb & 63, part = bb >> 6;          // parts of b: bb, bb+64,.. same XCD
  int lane = tid & 63, wave = tid >> 6;     // 2 waves
  int myword = (part << 1) + wave;
  int gn = (part << 7) + tid;               // my global neuron
  int t4 = gn << 2;                         // byte col offset in a w_recT row
  const char* wb = (const char*)w_recT;
  float v = 0.f, z = 0.f;
  float xcur = 0.f, xn1 = 0.f;
  if (tid < 8) zbuf[tid] = 0ull;
  if (PRE) {
    xcur = xproj[(size_t)(b * NSTEP) * N_REC + gn];
    if (NSTEP > 1) xn1 = xproj[(size_t)(b * NSTEP + 1) * N_REC + gn];
  } else {
    xrow[0][tid] = x[(size_t)(b * N_T) * N_IN + tid];
  }
  __syncthreads();
  for (int t = 0; t < NSTEP; ++t) {
    // ---- (1) fetch other parts' spike words for step t-1 ----
    if (t > 0 && wave == 0 && lane < 8) {
      int w = lane, wp = w >> 1;
      if (wp != part) {
        while (__hip_atomic_load(&gtag[((b << 2) + wp) * 2 + (w & 1)],
                                 __ATOMIC_ACQUIRE, __HIP_MEMORY_SCOPE_AGENT)
               < (unsigned int)t) {}
        zbuf[w] = __hip_atomic_load(
            &gmask[(((b << 1) + ((t - 1) & 1)) * 4 + wp) * 2 + (w & 1)],
            __ATOMIC_RELAXED, __HIP_MEMORY_SCOPE_AGENT);
      }
    }
    bar_lgkm();                         // zbuf complete (own words from t-1 end)
    // ---- (2) build compacted ascending list from the 8 words ----
    ull zw[8];
    #pragma unroll
    for (int w = 0; w < 8; ++w) zw[w] = zbuf[w];
    int pre[8]; int run = 0;
    #pragma unroll
    for (int w = 0; w < 8; ++w) { pre[w] = run; run += __popcll(zw[w]); }
    int ntot = run;
    #pragma unroll
    for (int u = 0; u < 4; ++u) {
      int g = tid + (u << 7);
      int w = g >> 6, bit = g & 63;
      if ((zw[w] >> bit) & 1ull) {
        int pos = pre[w] + __popcll(zw[w] & ((1ull << bit) - 1ull));
        list[pos] = g << 11;
      }
    }
    int np16 = (ntot + 15) & ~15;
    if (tid < np16 - ntot) list[ntot + tid] = SENT_OFF;
    bar_lgkm();                         // list visible; zbuf now reusable
    int nb = np16 >> 4;
    // ---- (3) input ----
    float xn2 = 0.f;
    if (PRE) {
      if (t + 2 < NSTEP)
        xn2 = xproj[(size_t)(b * NSTEP + t + 2) * N_REC + gn];
    } else {
      if (t + 1 < NSTEP)
        xrow[(t + 1) & 1][tid] = x[((size_t)b * N_T + t + 1) * N_IN + tid];
    }
    float xin;
    if (PRE) {
      xin = xcur;
    } else {
      xin = 0.f;
      const float* xr = xrow[t & 1];
      for (int k = 0; k < N_IN; ++k)    // sgemm chain, in-kernel (fallback)
        xin = fmaf(xr[k], w_inT[k * N_REC + gn], xin);
    }
    // ---- (4) gather: ascending-j __fadd_rn chain; width 16, depth 4 ----
    float rec = 0.f;
    {
      I16 I0, I1, I2, I3;
      F16R D0, D1, D2, D3;
      if (nb > 0) iload16(I0, list, 0);
      if (nb > 1) iload16(I1, list, 16);
      if (nb > 2) iload16(I2, list, 32);
      if (nb > 0) gload16i(D0, I0, wb, t4);
      if (nb > 1) gload16i(D1, I1, wb, t4);
      if (nb > 2) gload16i(D2, I2, wb, t4);
      if (nb > 3) iload16(I3, list, 48);
      int k = 0;
      while (k < nb) {
        rec = add16(rec, D0);
        if (k + 3 < nb) gload16i(D3, I3, wb, t4);
        if (k + 4 < nb) iload16(I0, list, (k + 4) << 4);
        ++k; if (k >= nb) break;
        rec = add16(rec, D1);
        if (k + 3 < nb) gload16i(D0, I0, wb, t4);
        if (k + 4 < nb) iload16(I1, list, (k + 4) << 4);
        ++k; if (k >= nb) break;
        rec = add16(rec, D2);
        if (k + 3 < nb) gload16i(D1, I1, wb, t4);
        if (k + 4 < nb) iload16(I2, list, (k + 4) << 4);
        ++k; if (k >= nb) break;
        rec = add16(rec, D3);
        if (k + 3 < nb) gload16i(D2, I2, wb, t4);
        if (k + 4 < nb) iload16(I3, list, (k + 4) << 4);
        ++k;
      }
    }
    // ---- (5) np evaluation order: ((ALPHA*v + rec) + xin) - z ----
    float t1 = __fmul_rn(ALPHA_F, v);
    t1 = __fadd_rn(t1, rec);
    t1 = __fadd_rn(t1, xin);
    v  = __fsub_rn(t1, z);
    int on = v > 1.0f;
    z = on ? 1.0f : 0.0f;
    ull mask = __ballot(on);            // 64-bit word of this wave
    // ---- (6) publish ----
    if (lane == 0) {
      zmask[((size_t)b * NSTEP + t) * 8 + myword] = mask;  // output record
      zbuf[myword] = mask;                                  // own word, local
      __hip_atomic_store(
          &gmask[(((b << 1) + (t & 1)) * 4 + part) * 2 + wave], mask,
          __ATOMIC_RELAXED, __HIP_MEMORY_SCOPE_AGENT);
      __hip_atomic_store(&gtag[((b << 2) + part) * 2 + wave],
                         (unsigned int)(t + 1),
                         __ATOMIC_RELEASE, __HIP_MEMORY_SCOPE_AGENT);
    }
    xcur = xn1; xn1 = xn2;
  }
}

// ---- C: U[n][o] = sum_{j active} w_out[o][j]; w_out staged in LDS ----------
__global__ __launch_bounds__(256) void k_U(
    const ull* __restrict__ zmask, const float* __restrict__ w_out,
    float* __restrict__ U) {
  __shared__ float wT[N_REC][N_OUT];        // 40 KiB, wT[j][o] = w_out[o][j]
  int tid = threadIdx.x;
  for (int e = tid; e < N_REC * N_OUT; e += 256) {
    int j = e / N_OUT, o = e - j * N_OUT;
    wT[j][o] = w_out[o * N_REC + j];
  }
  __syncthreads();
  int n = blockIdx.x * 256 + tid;
  if (n >= N_B * NSTEP) return;
  ull m[8];
  #pragma unroll
  for (int w = 0; w < 8; ++w) m[w] = zmask[(size_t)n * 8 + w];
  float acc[N_OUT];
  #pragma unroll
  for (int o = 0; o < N_OUT; ++o) acc[o] = 0.f;
  #pragma unroll
  for (int w = 0; w < 8; ++w) {
    ull bits = m[w];
    while (bits) {
      int j = __builtin_ctzll(bits);
      bits &= bits - 1;
      const float4* r4 = (const float4*)&wT[(w << 6) + j][0];
      float4 r0 = r4[0], r1 = r4[1], r2 = r4[2], r3 = r4[3], r4v = r4[4];
      acc[0]  += r0.x;  acc[1]  += r0.y;  acc[2]  += r0.z;  acc[3]  += r0.w;
      acc[4]  += r1.x;  acc[5]  += r1.y;  acc[6]  += r1.z;  acc[7]  += r1.w;
      acc[8]  += r2.x;  acc[9]  += r2.y;  acc[10] += r2.z;  acc[11] += r2.w;
      acc[12] += r3.x;  acc[13] += r3.y;  acc[14] += r3.z;  acc[15] += r3.w;
      acc[16] += r4v.x; acc[17] += r4v.y; acc[18] += r4v.z; acc[19] += r4v.w;
    }
  }
  float4* Up = (float4*)(U + (size_t)n * N_OUT);
  Up[0] = make_float4(acc[0],  acc[1],  acc[2],  acc[3]);
  Up[1] = make_float4(acc[4],  acc[5],  acc[6],  acc[7]);
  Up[2] = make_float4(acc[8],  acc[9],  acc[10], acc[11]);
  Up[3] = make_float4(acc[12], acc[13], acc[14], acc[15]);
  Up[4] = make_float4(acc[16], acc[17], acc[18], acc[19]);
}

// ---- D: vo prefix scan, f32 strict np order: kappa*vo then +U --------------
__global__ __launch_bounds__(64) void k_voscan(
    const float* __restrict__ U, float* __restrict__ out) {
  int n = blockIdx.x * 64 + threadIdx.x;
  if (n >= N_B * N_OUT) return;
  int b = n / N_OUT, o = n - b * N_OUT;
  out[(size_t)(b * N_T) * N_OUT + o] = 0.f;      // vo[0] = 0
  float acc = 0.f;
  #pragma unroll 9
  for (int t = 0; t < NSTEP; ++t) {
    acc = __fadd_rn(__fmul_rn(KAPPA_F, acc),
                    U[(size_t)(b * NSTEP + t) * N_OUT + o]);
    out[(size_t)(b * N_T + t + 1) * N_OUT + o] = acc;
  }
}

// ---- E: in-place softmax over the 20 outputs (f32) -------------------------
__global__ __launch_bounds__(256) void k_softmax(float* __restrict__ out) {
  int n = blockIdx.x * 256 + threadIdx.x;
  if (n >= N_B * N_T) return;
  float* p = out + (size_t)n * N_OUT;
  float vals[N_OUT];
  #pragma unroll
  for (int o = 0; o < N_OUT; ++o) vals[o] = p[o];
  float mx = vals[0];
  #pragma unroll
  for (int o = 1; o < N_OUT; ++o) mx = fmaxf(mx, vals[o]);
  float s = 0.f;
  #pragma unroll
  for (int o = 0; o < N_OUT; ++o) { vals[o] = expf(vals[o] - mx); s += vals[o]; }
  float inv = 1.0f / s;
  #pragma unroll
  for (int o = 0; o < N_OUT; ++o) p[o] = vals[o] * inv;
}

extern "C" void kernel_launch(void* const* d_in, const int* in_sizes, int n_in,
                              void* d_out, int out_size, void* d_ws, size_t ws_size,
                              hipStream_t stream) {
  // defensive remap: match by element count, any order/subset
  int ix = -1, iwin = -1, iwrec = -1, iwout = -1;
  for (int i = 0; i < n_in; ++i) {
    long long s = in_sizes[i];
    if (s == (long long)N_B * N_T * N_IN) ix = i;
    else if (s == N_REC * N_IN)  iwin = i;
    else if (s == N_REC * N_REC) iwrec = i;
    else if (s == N_OUT * N_REC) iwout = i;
  }
  if (ix < 0 || iwin < 0 || iwrec < 0 || iwout < 0) {
    if (n_in >= 5) { ix = 0; iwin = 2; iwrec = 3; iwout = 4; }
    else           { ix = 0; iwin = 1; iwrec = 2; iwout = 3; }
  }
  const float* x     = (const float*)d_in[ix];
  const float* w_in  = (const float*)d_in[iwin];
  const float* w_rec = (const float*)d_in[iwrec];
  const float* w_out = (const float*)d_in[iwout];
  float* out = (float*)d_out;
  char* ws = (char*)d_ws;

  float* w_inT  = (float*)(ws + OFF_WINT);
  float* w_recT = (float*)(ws + OFF_WRECT);
  ull*   zmask  = (ull*)(ws + OFF_ZMASK);
  float* U      = (float*)(ws + OFF_U);
  ull*   gmask  = (ull*)(ws + OFF_GMASK);
  unsigned int* gtag = (unsigned int*)(ws + OFF_GTAG);
  float* xproj  = (float*)(ws + OFF_XPROJ);

  // 65,536 + 262,656 + 512 = 328,704 elements -> 1284 blocks x 256
  k_setup<<<1284, 256, 0, stream>>>(w_in, w_rec, w_inT, w_recT, gtag);
  if (ws_size >= NEED_PRE) {
    k_xprojE<<<1332, 256, 0, stream>>>(x, w_inT, xproj);   // 63936/48
    k_scanS<true><<<256, 128, 0, stream>>>(xproj, x, w_inT, w_recT,
                                           zmask, gmask, gtag);
  } else {
    k_scanS<false><<<256, 128, 0, stream>>>(xproj, x, w_inT, w_recT,
                                            zmask, gmask, gtag);
  }
  k_U<<<250, 256, 0, stream>>>(zmask, w_out, U);
  k_voscan<<<20, 64, 0, stream>>>(U, out);
  k_softmax<<<250, 256, 0, stream>>>(out);
}

// Round 12
// 2272.441 us; speedup vs baseline: 4.2886x; 4.2886x over previous
//
#include <hip/hip_runtime.h>
#include <cstdint>
#include <cstddef>

#define N_IN   128
#define N_REC  512
#define N_OUT  20
#define N_T    1000
#define N_B    64
#define NSTEP  999
// f32(exp(-0.05)) — what numpy/jax actually multiply f32 arrays by
#define ALPHA_F 0.95122945308685302734375f
#define KAPPA_F 0.95122945308685302734375f

typedef unsigned long long ull;

// ---- ws layout (bytes) ----
#define OFF_WINT   0ull            // 128*512*4  = 262,144   w_inT[k][i]
#define OFF_WRECT  262144ull       // 513*512*4  = 1,050,624 w_recT[j][i], diag=0, row512=0
#define OFF_ZMASK  1312768ull      // 64*999*8*8 = 4,091,904
#define OFF_U      5404672ull      // 64*999*20*4= 5,114,880
#define OFF_XPROJ  10519552ull     // 64*999*512*4 = 130,940,928
#define NEED_PRE   (OFF_XPROJ + 130940928ull)

#define SENT_OFF   (512 << 11)     // byte offset of the zero pad row

// light barrier: LDS-ordering only, no vmcnt(0) drain
__device__ __forceinline__ void bar_lgkm() {
  asm volatile("s_waitcnt lgkmcnt(0)" ::: "memory");
  __builtin_amdgcn_s_barrier();
}

// ---------------- setup: transposes (+zero diag, +zero pad row 512) ---------
__global__ __launch_bounds__(256) void k_setup(
    const float* __restrict__ w_in, const float* __restrict__ w_rec,
    float* __restrict__ w_inT, float* __restrict__ w_recT) {
  int idx = blockIdx.x * 256 + threadIdx.x;
  if (idx < N_IN * N_REC) {                     // w_inT[k][i] = w_in[i][k]
    int k = idx >> 9, i = idx & 511;
    w_inT[idx] = w_in[i * N_IN + k];
  } else if (idx < N_IN * N_REC + 513 * N_REC) {
    int r = idx - N_IN * N_REC;                 // w_recT[j][i] = w_rec[i][j]*(i!=j)
    int j = r >> 9, i = r & 511;
    w_recT[r] = (j < N_REC && i != j) ? w_rec[i * N_REC + j] : 0.0f;
  }
}

// ---- A: xproj[s][i] = sequential ascending-k f32 FMA chain (BLAS order) ----
#define XROWS 48
__global__ __launch_bounds__(256) void k_xprojE(
    const float* __restrict__ x, const float* __restrict__ w_inT,
    float* __restrict__ xproj) {
  __shared__ float xs[XROWS][N_IN];       // 24 KiB
  int tid = threadIdx.x;
  int R0 = blockIdx.x * XROWS;
  #pragma unroll
  for (int u = 0; u < 6; ++u) {
    int id = tid + u * 256;               // 1536 float4 slots = 48 rows
    int rr = id >> 5, c = id & 31;
    int s = R0 + rr;
    int b = s / NSTEP, t = s - b * NSTEP;
    float4 xv = ((const float4*)x)[(size_t)(b * N_T + t) * 32 + c];
    xs[rr][4 * c]     = xv.x;
    xs[rr][4 * c + 1] = xv.y;
    xs[rr][4 * c + 2] = xv.z;
    xs[rr][4 * c + 3] = xv.w;
  }
  __syncthreads();
  float acc[XROWS][2];
  #pragma unroll
  for (int r = 0; r < XROWS; ++r) { acc[r][0] = 0.f; acc[r][1] = 0.f; }
  // single accumulator per output, ascending k, fused mul-add: sgemm order
  for (int k = 0; k < N_IN; ++k) {
    float wa = w_inT[k * N_REC + tid];
    float wb = w_inT[k * N_REC + tid + 256];
    #pragma unroll
    for (int r = 0; r < XROWS; ++r) {
      acc[r][0] = fmaf(xs[r][k], wa, acc[r][0]);
      acc[r][1] = fmaf(xs[r][k], wb, acc[r][1]);
    }
  }
  #pragma unroll
  for (int r = 0; r < XROWS; ++r) {
    size_t o0 = (size_t)(R0 + r) * N_REC + tid;
    xproj[o0]       = acc[r][0];
    xproj[o0 + 256] = acc[r][1];
  }
}

// ---- gather primitives: 16 indices (byte offsets) / 16 saddr loads ---------
struct F16R { float f[16]; };
struct I16  { int4 a, b, c, d; };

__device__ __forceinline__ void iload16(I16& r, const int* __restrict__ L, int base) {
  r.a = *(const int4*)(L + base);
  r.b = *(const int4*)(L + base + 4);
  r.c = *(const int4*)(L + base + 8);
  r.d = *(const int4*)(L + base + 12);
}

// addr = uniform w_recT base + u32(off_from_list + tid*4)  -> saddr load form
__device__ __forceinline__ void gload16i(F16R& r, const I16& I,
                                         const char* __restrict__ wb, int t4) {
  r.f[0]  = *(const float*)(wb + (uint32_t)(I.a.x + t4));
  r.f[1]  = *(const float*)(wb + (uint32_t)(I.a.y + t4));
  r.f[2]  = *(const float*)(wb + (uint32_t)(I.a.z + t4));
  r.f[3]  = *(const float*)(wb + (uint32_t)(I.a.w + t4));
  r.f[4]  = *(const float*)(wb + (uint32_t)(I.b.x + t4));
  r.f[5]  = *(const float*)(wb + (uint32_t)(I.b.y + t4));
  r.f[6]  = *(const float*)(wb + (uint32_t)(I.b.z + t4));
  r.f[7]  = *(const float*)(wb + (uint32_t)(I.b.w + t4));
  r.f[8]  = *(const float*)(wb + (uint32_t)(I.c.x + t4));
  r.f[9]  = *(const float*)(wb + (uint32_t)(I.c.y + t4));
  r.f[10] = *(const float*)(wb + (uint32_t)(I.c.z + t4));
  r.f[11] = *(const float*)(wb + (uint32_t)(I.c.w + t4));
  r.f[12] = *(const float*)(wb + (uint32_t)(I.d.x + t4));
  r.f[13] = *(const float*)(wb + (uint32_t)(I.d.y + t4));
  r.f[14] = *(const float*)(wb + (uint32_t)(I.d.z + t4));
  r.f[15] = *(const float*)(wb + (uint32_t)(I.d.w + t4));
}

__device__ __forceinline__ float add16(float rec, const F16R& r) {
  #pragma unroll
  for (int u = 0; u < 16; ++u) rec = __fadd_rn(rec, r.f[u]);
  return rec;
}

// ---- B: scan; dbl-buffered list; 16-wide depth-4 rotated pipeline ----------
// launch_bounds(512,1): only 64 blocks exist -> 1 block/CU; give the register
// allocator the full 256-VGPR budget so the depth-4 rotation stays in flight
// (R9's 80-VGPR allocation collapsed it; R10's static 8x16 overflowed it).
template <bool PRE>
__global__ __launch_bounds__(512, 1) void k_scanE(
    const float* __restrict__ xproj, const float* __restrict__ x,
    const float* __restrict__ w_inT, const float* __restrict__ w_recT,
    ull* __restrict__ zmask) {
  __shared__ __align__(16) int list[2][512];   // byte offsets, ascending j
  __shared__ ull zbuf[2][8];
  __shared__ float xrow[2][N_IN];              // PRE=false only
  int tid = threadIdx.x, b = blockIdx.x;
  int lane = tid & 63, wave = tid >> 6;
  int t4 = tid << 2;
  const char* wb = (const char*)w_recT;
  float v = 0.f, z = 0.f;
  int nb = 0;
  float xcur = 0.f, xn1 = 0.f;
  if (PRE) {
    xcur = xproj[(size_t)(b * NSTEP) * N_REC + tid];
    if (NSTEP > 1) xn1 = xproj[(size_t)(b * NSTEP + 1) * N_REC + tid];
  } else {
    if (tid < N_IN) xrow[0][tid] = x[(size_t)(b * N_T) * N_IN + tid];
  }
  __syncthreads();
  for (int t = 0; t < NSTEP; ++t) {
    int p = t & 1, q = p ^ 1;
    const int* L = list[p];
    // prefetch input 2 steps ahead (HBM latency cover)
    float xn2 = 0.f;
    if (PRE) {
      if (t + 2 < NSTEP)
        xn2 = xproj[(size_t)(b * NSTEP + t + 2) * N_REC + tid];
    } else {
      if (tid < N_IN && t + 1 < NSTEP)
        xrow[(t + 1) & 1][tid] = x[((size_t)b * N_T + t + 1) * N_IN + tid];
    }
    float xin;
    if (PRE) {
      xin = xcur;
    } else {
      xin = 0.f;
      const float* xr = xrow[t & 1];
      for (int k = 0; k < N_IN; ++k)        // sgemm chain, in-kernel
        xin = fmaf(xr[k], w_inT[k * N_REC + tid], xin);
    }
    // ---- gather: ascending-j __fadd_rn chain; width 16, depth 4 ----
    float rec = 0.f;
    {
      I16 I0, I1, I2, I3;
      F16R D0, D1, D2, D3;
      if (nb > 0) iload16(I0, L, 0);
      if (nb > 1) iload16(I1, L, 16);
      if (nb > 2) iload16(I2, L, 32);
      if (nb > 0) gload16i(D0, I0, wb, t4);
      if (nb > 1) gload16i(D1, I1, wb, t4);
      if (nb > 2) gload16i(D2, I2, wb, t4);
      if (nb > 3) iload16(I3, L, 48);
      int k = 0;
      while (k < nb) {
        rec = add16(rec, D0);
        if (k + 3 < nb) gload16i(D3, I3, wb, t4);
        if (k + 4 < nb) iload16(I0, L, (k + 4) << 4);
        ++k; if (k >= nb) break;
        rec = add16(rec, D1);
        if (k + 3 < nb) gload16i(D0, I0, wb, t4);
        if (k + 4 < nb) iload16(I1, L, (k + 4) << 4);
        ++k; if (k >= nb) break;
        rec = add16(rec, D2);
        if (k + 3 < nb) gload16i(D1, I1, wb, t4);
        if (k + 4 < nb) iload16(I2, L, (k + 4) << 4);
        ++k; if (k >= nb) break;
        rec = add16(rec, D3);
        if (k + 3 < nb) gload16i(D2, I2, wb, t4);
        if (k + 4 < nb) iload16(I3, L, (k + 4) << 4);
        ++k;
      }
    }
    // ---- np evaluation order: ((ALPHA*v + rec) + xin) - z ----
    float t1 = __fmul_rn(ALPHA_F, v);
    t1 = __fadd_rn(t1, rec);
    t1 = __fadd_rn(t1, xin);
    v  = __fsub_rn(t1, z);
    int on = v > 1.0f;
    z = on ? 1.0f : 0.0f;
    ull mask = __ballot(on);
    if (lane == 0) {
      zmask[((size_t)b * NSTEP + t) * 8 + wave] = mask;   // fire-and-forget
      zbuf[q][wave] = mask;
    }
    bar_lgkm();                      // (1) masks visible; old-list reads done
    int base = 0, ntot = 0;
    #pragma unroll
    for (int w = 0; w < 8; ++w) {
      ull mw = zbuf[q][w];
      int c = __popcll(mw);
      if (w < wave) base += c;
      ntot += c;
    }
    if (on) {
      int pc = __popcll(mask & ((1ull << lane) - 1));
      list[q][base + pc] = tid << 11;          // byte offset, ascending j
    }
    int np16 = (ntot + 15) & ~15;
    if (tid >= ntot && tid < np16) list[q][tid] = SENT_OFF;  // zero row
    bar_lgkm();                      // (2) new list visible
    nb = np16 >> 4;
    xcur = xn1; xn1 = xn2;
  }
}

// ---- C: U[n][o] = sum_{j active} w_out[o][j]; w_out staged in LDS ----------
__global__ __launch_bounds__(256) void k_U(
    const ull* __restrict__ zmask, const float* __restrict__ w_out,
    float* __restrict__ U) {
  __shared__ float wT[N_REC][N_OUT];        // 40 KiB, wT[j][o] = w_out[o][j]
  int tid = threadIdx.x;
  for (int e = tid; e < N_REC * N_OUT; e += 256) {
    int j = e / N_OUT, o = e - j * N_OUT;
    wT[j][o] = w_out[o * N_REC + j];
  }
  __syncthreads();
  int n = blockIdx.x * 256 + tid;
  if (n >= N_B * NSTEP) return;
  ull m[8];
  #pragma unroll
  for (int w = 0; w < 8; ++w) m[w] = zmask[(size_t)n * 8 + w];
  float acc[N_OUT];
  #pragma unroll
  for (int o = 0; o < N_OUT; ++o) acc[o] = 0.f;
  #pragma unroll
  for (int w = 0; w < 8; ++w) {
    ull bits = m[w];
    while (bits) {
      int j = __builtin_ctzll(bits);
      bits &= bits - 1;
      const float4* r4 = (const float4*)&wT[(w << 6) + j][0];
      float4 r0 = r4[0], r1 = r4[1], r2 = r4[2], r3 = r4[3], r4v = r4[4];
      acc[0]  += r0.x;  acc[1]  += r0.y;  acc[2]  += r0.z;  acc[3]  += r0.w;
      acc[4]  += r1.x;  acc[5]  += r1.y;  acc[6]  += r1.z;  acc[7]  += r1.w;
      acc[8]  += r2.x;  acc[9]  += r2.y;  acc[10] += r2.z;  acc[11] += r2.w;
      acc[12] += r3.x;  acc[13] += r3.y;  acc[14] += r3.z;  acc[15] += r3.w;
      acc[16] += r4v.x; acc[17] += r4v.y; acc[18] += r4v.z; acc[19] += r4v.w;
    }
  }
  float4* Up = (float4*)(U + (size_t)n * N_OUT);
  Up[0] = make_float4(acc[0],  acc[1],  acc[2],  acc[3]);
  Up[1] = make_float4(acc[4],  acc[5],  acc[6],  acc[7]);
  Up[2] = make_float4(acc[8],  acc[9],  acc[10], acc[11]);
  Up[3] = make_float4(acc[12], acc[13], acc[14], acc[15]);
  Up[4] = make_float4(acc[16], acc[17], acc[18], acc[19]);
}

// ---- D: vo prefix scan, f32 strict np order: kappa*vo then +U --------------
__global__ __launch_bounds__(64) void k_voscan(
    const float* __restrict__ U, float* __restrict__ out) {
  int n = blockIdx.x * 64 + threadIdx.x;
  if (n >= N_B * N_OUT) return;
  int b = n / N_OUT, o = n - b * N_OUT;
  out[(size_t)(b * N_T) * N_OUT + o] = 0.f;      // vo[0] = 0
  float acc = 0.f;
  #pragma unroll 9
  for (int t = 0; t < NSTEP; ++t) {
    acc = __fadd_rn(__fmul_rn(KAPPA_F, acc),
                    U[(size_t)(b * NSTEP + t) * N_OUT + o]);
    out[(size_t)(b * N_T + t + 1) * N_OUT + o] = acc;
  }
}

// ---- E: in-place softmax over the 20 outputs (f32) -------------------------
__global__ __launch_bounds__(256) void k_softmax(float* __restrict__ out) {
  int n = blockIdx.x * 256 + threadIdx.x;
  if (n >= N_B * N_T) return;
  float* p = out + (size_t)n * N_OUT;
  float vals[N_OUT];
  #pragma unroll
  for (int o = 0; o < N_OUT; ++o) vals[o] = p[o];
  float mx = vals[0];
  #pragma unroll
  for (int o = 1; o < N_OUT; ++o) mx = fmaxf(mx, vals[o]);
  float s = 0.f;
  #pragma unroll
  for (int o = 0; o < N_OUT; ++o) { vals[o] = expf(vals[o] - mx); s += vals[o]; }
  float inv = 1.0f / s;
  #pragma unroll
  for (int o = 0; o < N_OUT; ++o) p[o] = vals[o] * inv;
}

extern "C" void kernel_launch(void* const* d_in, const int* in_sizes, int n_in,
                              void* d_out, int out_size, void* d_ws, size_t ws_size,
                              hipStream_t stream) {
  // defensive remap: match by element count, any order/subset
  int ix = -1, iwin = -1, iwrec = -1, iwout = -1;
  for (int i = 0; i < n_in; ++i) {
    long long s = in_sizes[i];
    if (s == (long long)N_B * N_T * N_IN) ix = i;
    else if (s == N_REC * N_IN)  iwin = i;
    else if (s == N_REC * N_REC) iwrec = i;
    else if (s == N_OUT * N_REC) iwout = i;
  }
  if (ix < 0 || iwin < 0 || iwrec < 0 || iwout < 0) {
    if (n_in >= 5) { ix = 0; iwin = 2; iwrec = 3; iwout = 4; }
    else           { ix = 0; iwin = 1; iwrec = 2; iwout = 3; }
  }
  const float* x     = (const float*)d_in[ix];
  const float* w_in  = (const float*)d_in[iwin];
  const float* w_rec = (const float*)d_in[iwrec];
  const float* w_out = (const float*)d_in[iwout];
  float* out = (float*)d_out;
  char* ws = (char*)d_ws;

  float* w_inT  = (float*)(ws + OFF_WINT);
  float* w_recT = (float*)(ws + OFF_WRECT);
  ull*   zmask  = (ull*)(ws + OFF_ZMASK);
  float* U      = (float*)(ws + OFF_U);
  float* xproj  = (float*)(ws + OFF_XPROJ);

  // 65,536 + 262,656 = 328,192 elements -> 1282 blocks x 256
  k_setup<<<1282, 256, 0, stream>>>(w_in, w_rec, w_inT, w_recT);
  if (ws_size >= NEED_PRE) {
    k_xprojE<<<1332, 256, 0, stream>>>(x, w_inT, xproj);   // 63936/48
    k_scanE<true><<<N_B, 512, 0, stream>>>(xproj, x, w_inT, w_recT, zmask);
  } else {
    k_scanE<false><<<N_B, 512, 0, stream>>>(xproj, x, w_inT, w_recT, zmask);
  }
  k_U<<<250, 256, 0, stream>>>(zmask, w_out, U);
  k_voscan<<<20, 64, 0, stream>>>(U, out);
  k_softmax<<<250, 256, 0, stream>>>(out);
}